// Round 6
// baseline (360.324 us; speedup 1.0000x reference)
//
#include <hip/hip_runtime.h>

#define B_TOT 8192
#define T_LEN 1024
#define HID 10

typedef float v2f __attribute__((ext_vector_type(2)));

// Force VOP3P packed fp32 math (LLVM scalarizes ext-vector fp32 fma otherwise).
__device__ __forceinline__ v2f pk_mul(v2f a, v2f b) {
    v2f d;
    asm("v_pk_mul_f32 %0, %1, %2" : "=v"(d) : "v"(a), "v"(b));
    return d;
}
__device__ __forceinline__ v2f pk_fma(v2f a, v2f b, v2f c) {
    v2f d;
    asm("v_pk_fma_f32 %0, %1, %2, %3" : "=v"(d) : "v"(a), "v"(b), "v"(c));
    return d;
}

// Broadcast lane K (0..15) of each row-of-16 to the whole row (VALU DPP, no LDS).
#define BCAST16(v, K)                                                         \
    __int_as_float(__builtin_amdgcn_update_dpp(                               \
        __float_as_int(v), __float_as_int(v), 0x150 | (K), 0xF, 0xF, false))

// Layout: 16 lanes per batch (lanes 0..9 active, unit j each), 4 batches/wave.
// v2f packs k-PAIRS: per gate q, acc.x sums even k, acc.y odd k; pair 5 = {x,1}
// folds the input and bias terms. h broadcast pairs built by 2 DPP movs each.
// Activations: 5 exp2 + 3 rcp via merged rationals:
//   sig(i)*tanh(g) = (eg-1)/((1+ei)(1+eg)),  sig(o)*tanh(c) = (eC-1)/((1+eo)(1+eC))
// Cell state kept scaled: C = 2*log2(e)*c.
__global__ __launch_bounds__(256) void lstm_fused_kernel(
    const float* __restrict__ x,      // [B, T]
    const float* __restrict__ W_ih,   // [40, 1]
    const float* __restrict__ W_hh,   // [40, 10]  gate order i,f,g,o
    const float* __restrict__ b_ih,   // [40]
    const float* __restrict__ b_hh,   // [40]
    const float* __restrict__ W_lin,  // [1, 10]
    const float* __restrict__ b_lin,  // [1]
    float* __restrict__ out)          // [B]
{
    const int tid  = threadIdx.x;
    const int j16  = tid & 15;
    const int b    = blockIdx.x * 16 + (tid >> 4);
    const bool act = (j16 < HID);
    const int j    = act ? j16 : 0;           // idle lanes do clamped harmless work

    const float NL = -1.4426950408889634f;    // -log2(e): sigmoid gates i,f,o
    const float TL =  2.8853900817779268f;    // 2*log2(e): tanh gate g / C scale

    // w[q][0..4] = k-pair weights (pre-scaled), w[q][5] = {W_ih*s, (b_ih+b_hh)*s}
    v2f w[4][6];
#pragma unroll
    for (int q = 0; q < 4; ++q) {
        const float sc = (q == 2) ? TL : NL;
        const int r = q * HID + j;
#pragma unroll
        for (int kp = 0; kp < 5; ++kp)
            w[q][kp] = (v2f){sc * W_hh[r * HID + 2 * kp],
                             sc * W_hh[r * HID + 2 * kp + 1]};
        w[q][5] = (v2f){sc * W_ih[r], sc * (b_ih[r] + b_hh[r])};
    }
    // out = sum_j c_j*W_lin_j + b_lin;  c = C/(2 log2 e) folded into wl.
    const float wl = act ? W_lin[j] * 0.34657359027997264f : 0.0f;

    float h = 0.0f, C = 0.0f;
    const float* xb = x + (size_t)b * T_LEN;

#define LSTM_STEP(xv)                                                         \
    {                                                                         \
        v2f hp0, hp1, hp2, hp3, hp4, hx;                                      \
        hp0.x = BCAST16(h, 0); hp0.y = BCAST16(h, 1);                         \
        hp1.x = BCAST16(h, 2); hp1.y = BCAST16(h, 3);                         \
        hp2.x = BCAST16(h, 4); hp2.y = BCAST16(h, 5);                         \
        hp3.x = BCAST16(h, 6); hp3.y = BCAST16(h, 7);                         \
        hp4.x = BCAST16(h, 8); hp4.y = BCAST16(h, 9);                         \
        hx.x  = (xv);          hx.y  = 1.0f;                                  \
        v2f q0 = pk_mul(w[0][0], hp0), q1 = pk_mul(w[1][0], hp0);             \
        v2f q2 = pk_mul(w[2][0], hp0), q3 = pk_mul(w[3][0], hp0);             \
        q0 = pk_fma(w[0][1], hp1, q0); q1 = pk_fma(w[1][1], hp1, q1);         \
        q2 = pk_fma(w[2][1], hp1, q2); q3 = pk_fma(w[3][1], hp1, q3);         \
        q0 = pk_fma(w[0][2], hp2, q0); q1 = pk_fma(w[1][2], hp2, q1);         \
        q2 = pk_fma(w[2][2], hp2, q2); q3 = pk_fma(w[3][2], hp2, q3);         \
        q0 = pk_fma(w[0][3], hp3, q0); q1 = pk_fma(w[1][3], hp3, q1);         \
        q2 = pk_fma(w[2][3], hp3, q2); q3 = pk_fma(w[3][3], hp3, q3);         \
        q0 = pk_fma(w[0][4], hp4, q0); q1 = pk_fma(w[1][4], hp4, q1);         \
        q2 = pk_fma(w[2][4], hp4, q2); q3 = pk_fma(w[3][4], hp4, q3);         \
        q0 = pk_fma(w[0][5], hx, q0);  q1 = pk_fma(w[1][5], hx, q1);          \
        q2 = pk_fma(w[2][5], hx, q2);  q3 = pk_fma(w[3][5], hx, q3);          \
        float a0 = q0.x + q0.y;                 /* -i_raw * log2e        */   \
        float a1 = q1.x + q1.y;                 /* -f_raw * log2e        */   \
        float a2 = fminf(q2.x + q2.y, 80.0f);   /*  g_raw * 2log2e       */   \
        float a3 = q3.x + q3.y;                 /* -o_raw * log2e        */   \
        float ei = __builtin_amdgcn_exp2f(a0);                                \
        float ef = __builtin_amdgcn_exp2f(a1);                                \
        float eg = __builtin_amdgcn_exp2f(a2);                                \
        float eo = __builtin_amdgcn_exp2f(a3);                                \
        float fg = __builtin_amdgcn_rcpf(1.0f + ef);                          \
        float rp = __builtin_amdgcn_rcpf((1.0f + ei) * (1.0f + eg));          \
        float igg = (eg - 1.0f) * rp * TL;      /* 2L * sig(i)*tanh(g)   */   \
        C = fminf(fmaf(fg, C, igg), 80.0f);                                   \
        float eC = __builtin_amdgcn_exp2f(C);                                 \
        float rq = __builtin_amdgcn_rcpf((1.0f + eo) * (1.0f + eC));          \
        h = (eC - 1.0f) * rq;                   /* sig(o)*tanh(c)        */   \
    }

    float4 xq = *reinterpret_cast<const float4*>(xb);   // steps 0..3
    int t = 0;
    for (; t < T_LEN - 4; t += 4) {
        float4 xn = *reinterpret_cast<const float4*>(xb + t + 4);  // prefetch
        LSTM_STEP(xq.x)
        LSTM_STEP(xq.y)
        LSTM_STEP(xq.z)
        LSTM_STEP(xq.w)
        xq = xn;
    }
    LSTM_STEP(xq.x)
    LSTM_STEP(xq.y)
    LSTM_STEP(xq.z)
    LSTM_STEP(xq.w)
#undef LSTM_STEP

    // out[b] = dot(c, W_lin) + b_lin   (reduce across the 16-lane group)
    float v = act ? C * wl : 0.0f;
#pragma unroll
    for (int s = 1; s < 16; s <<= 1) v += __shfl_xor(v, s, 16);
    if (j16 == 0) out[b] = v + b_lin[0];
}

extern "C" void kernel_launch(void* const* d_in, const int* in_sizes, int n_in,
                              void* d_out, int out_size, void* d_ws, size_t ws_size,
                              hipStream_t stream) {
    const float* x     = (const float*)d_in[0];
    const float* W_ih  = (const float*)d_in[1];
    const float* W_hh  = (const float*)d_in[2];
    const float* b_ih  = (const float*)d_in[3];
    const float* b_hh  = (const float*)d_in[4];
    const float* W_lin = (const float*)d_in[5];
    const float* b_lin = (const float*)d_in[6];
    float* out = (float*)d_out;

    // 16 batches per 256-thread block -> 512 blocks, 2048 waves (2/SIMD, balanced).
    dim3 grid(B_TOT / 16), block(256);
    hipLaunchKernelGGL(lstm_fused_kernel, grid, block, 0, stream,
                       x, W_ih, W_hh, b_ih, b_hh, W_lin, b_lin, out);
}

// Round 7
// 355.638 us; speedup vs baseline: 1.0132x; 1.0132x over previous
//
#include <hip/hip_runtime.h>

#define B_TOT 8192
#define T_LEN 1024
#define HID 10
#define BPW 6   // batches per wave: 6 groups x 10 lanes, lanes 60..63 idle

// Dense 6x10 layout, one wave per block (no barriers). h broadcast via LDS:
// each lane writes its h (ds_write_b32), then reads k-PAIRS with ds_read_b64
// (all 10 lanes of a group read the same address -> broadcast, conflict-free).
// Weights pre-scaled by exp2 args (NL=-log2e for i,f,o; TL=2log2e for g);
// cell state kept scaled C = 2*log2(e)*c. Activations: 5 exp2 + 3 rcp
// (merged rationals), clamped at 80 to avoid inf*0.
__global__ __launch_bounds__(64) void lstm_fused_kernel(
    const float* __restrict__ x,      // [B, T]
    const float* __restrict__ W_ih,   // [40, 1]
    const float* __restrict__ W_hh,   // [40, 10]  gate order i,f,g,o
    const float* __restrict__ b_ih,   // [40]
    const float* __restrict__ b_hh,   // [40]
    const float* __restrict__ W_lin,  // [1, 10]
    const float* __restrict__ b_lin,  // [1]
    float* __restrict__ out)          // [B]
{
    const int lane = threadIdx.x;            // 0..63
    const int grp  = lane / HID;             // 0..6 (6 only for lanes 60..63)
    const int j    = lane - grp * HID;       // 0..9
    const bool act = (lane < BPW * HID);     // lanes 0..59
    const int g    = act ? grp : (BPW - 1);  // clamped group for addressing
    const int jj   = act ? j : 0;
    const int b    = blockIdx.x * BPW + g;
    const bool bok = act && (b < B_TOT);
    const int bc   = (b < B_TOT) ? b : (B_TOT - 1);
    const int rbase = g * HID;               // element base of this group in sh[]

    __shared__ float sh[64];

    const float NL = -1.4426950408889634f;   // -log2(e)
    const float TL =  2.8853900817779268f;   // 2*log2(e)

    // Per-lane weights for unit jj (rows q*10+jj), pre-scaled.
    float w0[HID], w1[HID], w2[HID], w3[HID];
    float wi0, wi1, wi2, wi3, bb0, bb1, bb2, bb3;
    {
        const int r0 = 0*HID+jj, r1 = 1*HID+jj, r2 = 2*HID+jj, r3 = 3*HID+jj;
        wi0 = NL*W_ih[r0]; wi1 = NL*W_ih[r1]; wi2 = TL*W_ih[r2]; wi3 = NL*W_ih[r3];
        bb0 = NL*(b_ih[r0]+b_hh[r0]); bb1 = NL*(b_ih[r1]+b_hh[r1]);
        bb2 = TL*(b_ih[r2]+b_hh[r2]); bb3 = NL*(b_ih[r3]+b_hh[r3]);
#pragma unroll
        for (int k = 0; k < HID; ++k) {
            w0[k] = NL*W_hh[r0*HID+k];
            w1[k] = NL*W_hh[r1*HID+k];
            w2[k] = TL*W_hh[r2*HID+k];
            w3[k] = NL*W_hh[r3*HID+k];
        }
    }
    const float wl = W_lin[jj] * 0.34657359027997264f;  // 1/(2 log2 e) folded

    float h = 0.0f, C = 0.0f;
    const float* xb = x + (size_t)bc * T_LEN;

// chain A: k-pairs 0..2 into a_q (after x/bias); chain B: pairs 3..4 into s_q.
#define LSTM_STEP(xv)                                                         \
    {                                                                         \
        sh[lane] = h;  /* ds_write; reads below wait via lgkmcnt */           \
        const float2* hp = (const float2*)(sh + rbase);                       \
        float2 p0 = hp[0], p1 = hp[1], p2 = hp[2], p3 = hp[3], p4 = hp[4];    \
        float a0 = fmaf((xv), wi0, bb0);                                      \
        float a1 = fmaf((xv), wi1, bb1);                                      \
        float a2 = fmaf((xv), wi2, bb2);                                      \
        float a3 = fmaf((xv), wi3, bb3);                                      \
        a0 = fmaf(w0[0],p0.x,a0); a1 = fmaf(w1[0],p0.x,a1);                   \
        a2 = fmaf(w2[0],p0.x,a2); a3 = fmaf(w3[0],p0.x,a3);                   \
        a0 = fmaf(w0[1],p0.y,a0); a1 = fmaf(w1[1],p0.y,a1);                   \
        a2 = fmaf(w2[1],p0.y,a2); a3 = fmaf(w3[1],p0.y,a3);                   \
        a0 = fmaf(w0[2],p1.x,a0); a1 = fmaf(w1[2],p1.x,a1);                   \
        a2 = fmaf(w2[2],p1.x,a2); a3 = fmaf(w3[2],p1.x,a3);                   \
        a0 = fmaf(w0[3],p1.y,a0); a1 = fmaf(w1[3],p1.y,a1);                   \
        a2 = fmaf(w2[3],p1.y,a2); a3 = fmaf(w3[3],p1.y,a3);                   \
        a0 = fmaf(w0[4],p2.x,a0); a1 = fmaf(w1[4],p2.x,a1);                   \
        a2 = fmaf(w2[4],p2.x,a2); a3 = fmaf(w3[4],p2.x,a3);                   \
        a0 = fmaf(w0[5],p2.y,a0); a1 = fmaf(w1[5],p2.y,a1);                   \
        a2 = fmaf(w2[5],p2.y,a2); a3 = fmaf(w3[5],p2.y,a3);                   \
        float s0 = w0[6]*p3.x, s1 = w1[6]*p3.x, s2 = w2[6]*p3.x, s3 = w3[6]*p3.x; \
        s0 = fmaf(w0[7],p3.y,s0); s1 = fmaf(w1[7],p3.y,s1);                   \
        s2 = fmaf(w2[7],p3.y,s2); s3 = fmaf(w3[7],p3.y,s3);                   \
        s0 = fmaf(w0[8],p4.x,s0); s1 = fmaf(w1[8],p4.x,s1);                   \
        s2 = fmaf(w2[8],p4.x,s2); s3 = fmaf(w3[8],p4.x,s3);                   \
        s0 = fmaf(w0[9],p4.y,s0); s1 = fmaf(w1[9],p4.y,s1);                   \
        s2 = fmaf(w2[9],p4.y,s2); s3 = fmaf(w3[9],p4.y,s3);                   \
        a0 += s0; a1 += s1; a3 += s3;                                         \
        a2 = fminf(a2 + s2, 80.0f);                                           \
        float ei = __builtin_amdgcn_exp2f(a0);                                \
        float ef = __builtin_amdgcn_exp2f(a1);                                \
        float eg = __builtin_amdgcn_exp2f(a2);                                \
        float eo = __builtin_amdgcn_exp2f(a3);                                \
        float fg = __builtin_amdgcn_rcpf(1.0f + ef);                          \
        float rp = __builtin_amdgcn_rcpf((1.0f + ei) * (1.0f + eg));          \
        float igg = (eg - 1.0f) * rp * TL;    /* 2L * sig(i)*tanh(g) */       \
        C = fminf(fmaf(fg, C, igg), 80.0f);                                   \
        float eC = __builtin_amdgcn_exp2f(C);                                 \
        float rq = __builtin_amdgcn_rcpf((1.0f + eo) * (1.0f + eC));          \
        h = (eC - 1.0f) * rq;                 /* sig(o)*tanh(c) */            \
    }

    float4 xq = *reinterpret_cast<const float4*>(xb);   // steps 0..3
    int t = 0;
    for (; t < T_LEN - 4; t += 4) {
        float4 xn = *reinterpret_cast<const float4*>(xb + t + 4);  // prefetch
        LSTM_STEP(xq.x)
        LSTM_STEP(xq.y)
        LSTM_STEP(xq.z)
        LSTM_STEP(xq.w)
        xq = xn;
    }
    LSTM_STEP(xq.x)
    LSTM_STEP(xq.y)
    LSTM_STEP(xq.z)
    LSTM_STEP(xq.w)
#undef LSTM_STEP

    // Epilogue: out[b] = sum_j C_j*wl_j + b_lin. Reuse sh; single wave ->
    // the ds_write completes (lgkmcnt) before the dependent reads, no barrier.
    sh[lane] = bok ? C * wl : 0.0f;
    if (bok && j == 0) {
        float s = b_lin[0];
#pragma unroll
        for (int u = 0; u < HID; ++u) s += sh[rbase + u];
        out[b] = s;
    }
}

extern "C" void kernel_launch(void* const* d_in, const int* in_sizes, int n_in,
                              void* d_out, int out_size, void* d_ws, size_t ws_size,
                              hipStream_t stream) {
    const float* x     = (const float*)d_in[0];
    const float* W_ih  = (const float*)d_in[1];
    const float* W_hh  = (const float*)d_in[2];
    const float* b_ih  = (const float*)d_in[3];
    const float* b_hh  = (const float*)d_in[4];
    const float* W_lin = (const float*)d_in[5];
    const float* b_lin = (const float*)d_in[6];
    float* out = (float*)d_out;

    // 6 batches per single-wave block -> 1366 blocks (last block tail-guarded).
    dim3 grid((B_TOT + BPW - 1) / BPW), block(64);
    hipLaunchKernelGGL(lstm_fused_kernel, grid, block, 0, stream,
                       x, W_ih, W_hh, b_ih, b_hh, W_lin, b_lin, out);
}